// Round 12
// baseline (28.490 us; speedup 1.0000x reference)
//
#include <hip/hip_runtime.h>
#include <math.h>
#include <float.h>

#define BB 16
#define NN 2382
#define TOT 38112           // BB*NN
#define NV4 9528            // TOT/4
#define EPSF 1e-5f
#define L2E 1.4426950408889634f
#define TT 32               // G-table nodes per batch
#define PITER 8
#define NXB 10              // n1 blocks per batch (10*256 >= NN)
#define NZB 38              // z-stat partial blocks
#define NB_OUT 149          // ceil(TOT/256)

// ws float layout
#define WS_KPQR 0           // float4[TOT] {K,P,q,r}
#define WS_ZS   152448      // 38 z partial sums
#define WS_ZQ   152512      // 38 z partial sumsq
#define WS_RNG  152576      // float4[16*10] {kmax,kmin,qmax,qmin}
#define WS_TAB  153216      // 16*32
#define WS_META 153728      // 16*2 {qmin, qinv}
#define WS_MOM  153792      // 16*5 {sG,sG2,sRG,sR,sR2}

// n0: 38 x 256, depth-1: z partial sums.
__global__ __launch_bounds__(256) void n0_zstats(
    const float* __restrict__ z, float* __restrict__ ws)
{
    __shared__ float sred[8];
    const int tid = threadIdx.x, wave = tid >> 6, lane = tid & 63;
    const int i = blockIdx.x*256 + tid;
    float s = 0.f, s2 = 0.f;
    if (i < NV4) {
        const float4 v = ((const float4*)z)[i];
        s  = v.x + v.y + v.z + v.w;
        s2 = fmaf(v.x,v.x, fmaf(v.y,v.y, fmaf(v.z,v.z, v.w*v.w)));
    }
    #pragma unroll
    for (int off=32; off; off>>=1){ s += __shfl_xor(s,off); s2 += __shfl_xor(s2,off); }
    if (lane==0){ sred[wave]=s; sred[4+wave]=s2; }
    __syncthreads();
    if (tid==0) {
        ws[WS_ZS+blockIdx.x] = sred[0]+sred[1]+sred[2]+sred[3];
        ws[WS_ZQ+blockIdx.x] = sred[4]+sred[5]+sred[6]+sred[7];
    }
}

// n1: grid (10,16) x 256, one item per thread: params (redundant, shallow),
// KPQR -> ws, per-block range partials -> ws.
__global__ __launch_bounds__(256) void n1_kpqr(
    const float* __restrict__ z,  const float* __restrict__ w1,
    const float* __restrict__ g1, const float* __restrict__ be1,
    const float* __restrict__ wq, const float* __restrict__ bqp,
    const float* __restrict__ wk, const float* __restrict__ bkp,
    const float* __restrict__ wv, const float* __restrict__ bv,
    const float* __restrict__ w2, const float* __restrict__ b2p,
    float* __restrict__ ws)
{
    __shared__ float sred[16];
    const int tid = threadIdx.x, wave = tid >> 6, lane = tid & 63;
    const int b = blockIdx.y;

    // z stats from partials (uniform)
    float zs = 0.f, zq = 0.f;
    #pragma unroll 2
    for (int j=0; j<NZB; ++j) { zs += ws[WS_ZS+j]; zq += ws[WS_ZQ+j]; }
    const float invn = 1.f/(float)TOT;
    const float mz = zs*invn;
    const float vz = zq*invn - mz*mz;

    // wave-parallel power iteration on M = wv^T wv (lane=(i,j))
    const int pi = lane >> 3, pj = lane & 7;
    float Mij = 0.f;
    #pragma unroll
    for (int o = 0; o < 8; ++o) Mij = fmaf(wv[o*8+pi], wv[o*8+pj], Mij);
    float u = 1.f, nr = 1.f;
    for (int it = 0; it < PITER; ++it) {
        float a = Mij*u;
        a += __shfl_xor(a,1); a += __shfl_xor(a,2); a += __shfl_xor(a,4);
        float bb = a*a;
        bb += __shfl_xor(bb,8); bb += __shfl_xor(bb,16); bb += __shfl_xor(bb,32);
        nr = sqrtf(bb);
        u = __shfl(a, pj<<3) / nr;
    }
    const float invsig = rsqrtf(nr);

    // derived params
    float n1v=0.f, nqv=0.f, nkv=0.f, n2v=0.f;
    #pragma unroll
    for (int h=0; h<8; ++h) {
        n1v = fmaf(w1[h], w1[h], n1v);
        nqv = fmaf(wq[h], wq[h], nqv);
        nkv = fmaf(wk[h], wk[h], nkv);
        n2v = fmaf(w2[h], w2[h], n2v);
    }
    n1v = sqrtf(n1v); nqv = sqrtf(nqv); nkv = sqrtf(nkv); n2v = sqrtf(n2v);

    float a1[8], c1[8], wqn[8], wkn[8], w2n[8], wvP[8];
    #pragma unroll
    for (int h=0; h<8; ++h) {
        const float w1n = w1[h]/n1v;
        const float rs = rsqrtf(fmaf(w1n*w1n, vz, EPSF));
        a1[h]  = w1n * rs * g1[h];
        c1[h]  = be1[h] - mz*a1[h];
        wqn[h] = wq[h]/nqv;
        wkn[h] = wk[h]/nkv;
        w2n[h] = w2[h]/n2v;
    }
    float bvP = 0.f;
    #pragma unroll
    for (int h=0; h<8; ++h) bvP = fmaf(w2n[h], bv[h], bvP);
    #pragma unroll
    for (int c=0; c<8; ++c) {
        float a = 0.f;
        #pragma unroll
        for (int h=0; h<8; ++h) a = fmaf(w2n[h], wv[h*8+c], a);
        wvP[c] = a * invsig;
    }

    const int n = blockIdx.x*256 + tid;
    float kk, pp, qq, rr;
    float lkmax=-FLT_MAX, lkmin=FLT_MAX, lqmax=-FLT_MAX, lqmin=FLT_MAX;
    if (n < NN) {
        const float zv = z[b*NN + n];
        float xh[8];
        #pragma unroll
        for (int h=0;h<8;++h) xh[h] = fmaxf(fmaf(a1[h], zv, c1[h]), 0.f);
        kk = bkp[0]; pp = bvP; qq = bqp[0]; rr = b2p[0];
        #pragma unroll
        for (int h=0;h<8;++h) {
            kk = fmaf(wkn[h], xh[h], kk);
            pp = fmaf(wvP[h], xh[h], pp);
            qq = fmaf(wqn[h], xh[h], qq);
            rr = fmaf(w2n[h], xh[h], rr);
        }
        ((float4*)(ws + WS_KPQR))[b*NN + n] = make_float4(kk, pp, qq, rr);
        lkmax = kk; lkmin = kk; lqmax = qq; lqmin = qq;
    }
    #pragma unroll
    for (int off=32; off; off>>=1) {
        lkmax = fmaxf(lkmax, __shfl_xor(lkmax, off));
        lkmin = fminf(lkmin, __shfl_xor(lkmin, off));
        lqmax = fmaxf(lqmax, __shfl_xor(lqmax, off));
        lqmin = fminf(lqmin, __shfl_xor(lqmin, off));
    }
    if (lane == 0) {
        sred[wave]    = lkmax; sred[4+wave]  = lkmin;
        sred[8+wave]  = lqmax; sred[12+wave] = lqmin;
    }
    __syncthreads();
    if (tid == 0) {
        const float kmax = fmaxf(fmaxf(sred[0],sred[1]), fmaxf(sred[2],sred[3]));
        const float kmin = fminf(fminf(sred[4],sred[5]), fminf(sred[6],sred[7]));
        const float qmax = fmaxf(fmaxf(sred[8],sred[9]), fmaxf(sred[10],sred[11]));
        const float qmin = fminf(fminf(sred[12],sred[13]), fminf(sred[14],sred[15]));
        ((float4*)(ws + WS_RNG))[b*NXB + blockIdx.x] =
            make_float4(kmax, kmin, qmax, qmin);
    }
}

// n2: grid (32 nodes, 16 batches) x 256: one G-table entry per block.
__global__ __launch_bounds__(256) void n2_table(
    const float* __restrict__ ws_in, float* __restrict__ ws)
{
    __shared__ float sred[8];
    const int tid = threadIdx.x, wave = tid >> 6, lane = tid & 63;
    const int node = blockIdx.x, b = blockIdx.y;

    // batch ranges from 10 partials (uniform)
    const float4* __restrict__ rng = (const float4*)(ws_in + WS_RNG);
    float kmax=-FLT_MAX, kmin=FLT_MAX, qmax=-FLT_MAX, qmin=FLT_MAX;
    #pragma unroll
    for (int j=0; j<NXB; ++j) {
        const float4 r = rng[b*NXB + j];
        kmax = fmaxf(kmax, r.x); kmin = fminf(kmin, r.y);
        qmax = fmaxf(qmax, r.z); qmin = fminf(qmin, r.w);
    }
    const float xq = fmaf((qmax-qmin), (float)node*(1.f/(float)(TT-1)), qmin);
    const float st = fmaxf(xq*kmax, xq*kmin);   // max_m xq*K[m]
    const float x2 = xq*L2E, st2 = st*L2E;

    const float4* __restrict__ kpqr = (const float4*)(ws_in + WS_KPQR);
    float den = 0.f, num = 0.f;
    #pragma unroll
    for (int j = 0; j < NXB; ++j) {             // independent L2 loads
        const int m = j*256 + tid;
        if (m < NN) {
            const float4 v = kpqr[b*NN + m];
            const float e = __builtin_amdgcn_exp2f(fmaf(x2, v.x, -st2));
            den += e; num = fmaf(e, v.y, num);
        }
    }
    #pragma unroll
    for (int off=32; off; off>>=1) {
        den += __shfl_xor(den, off);
        num += __shfl_xor(num, off);
    }
    if (lane == 0) { sred[wave] = den; sred[4+wave] = num; }
    __syncthreads();
    if (tid == 0) {
        const float d = sred[0]+sred[1]+sred[2]+sred[3];
        const float nm = sred[4]+sred[5]+sred[6]+sred[7];
        ws[WS_TAB + b*TT + node] = nm/d;        // den >= 1 (shifted)
    }
}

// n3: 16 x 1024, per batch: moments from table lerp; META.
__global__ __launch_bounds__(1024) void n3_moments(
    const float* __restrict__ ws_in, float* __restrict__ ws)
{
    __shared__ float sG[TT];
    __shared__ float sred[80];
    const int tid = threadIdx.x, wave = tid >> 6, lane = tid & 63;
    const int b = blockIdx.x;

    const float4* __restrict__ rng = (const float4*)(ws_in + WS_RNG);
    float qmax=-FLT_MAX, qmin=FLT_MAX;
    #pragma unroll
    for (int j=0; j<NXB; ++j) {
        const float4 r = rng[b*NXB + j];
        qmax = fmaxf(qmax, r.z); qmin = fminf(qmin, r.w);
    }
    const float qinv = (qmax > qmin) ? (float)(TT-1)/(qmax-qmin) : 0.f;
    if (tid < TT) sG[tid] = ws_in[WS_TAB + b*TT + tid];
    __syncthreads();

    const float4* __restrict__ kpqr = (const float4*)(ws_in + WS_KPQR);
    float mG=0.f, mG2=0.f, mRG=0.f, mR=0.f, mR2=0.f;
    for (int n = tid; n < NN; n += 1024) {
        const float4 v = kpqr[b*NN + n];
        float uu = fminf(fmaxf((v.z - qmin)*qinv, 0.f), (float)(TT-1));
        int i = (int)uu; if (i > TT-2) i = TT-2;
        const float f = uu - (float)i;
        const float g = fmaf(f, sG[i+1]-sG[i], sG[i]);
        mG += g;            mG2 = fmaf(g, g, mG2);
        mRG = fmaf(v.w, g, mRG);
        mR += v.w;          mR2 = fmaf(v.w, v.w, mR2);
    }
    #pragma unroll
    for (int off=32; off; off>>=1) {
        mG  += __shfl_xor(mG,  off);
        mG2 += __shfl_xor(mG2, off);
        mRG += __shfl_xor(mRG, off);
        mR  += __shfl_xor(mR,  off);
        mR2 += __shfl_xor(mR2, off);
    }
    if (lane == 0) {
        sred[wave] = mG;     sred[16+wave] = mG2;  sred[32+wave] = mRG;
        sred[48+wave] = mR;  sred[64+wave] = mR2;
    }
    __syncthreads();
    if (tid == 0) {
        float tG=0.f, tG2=0.f, tRG=0.f, tR=0.f, tR2=0.f;
        #pragma unroll
        for (int j=0; j<16; ++j) {
            tG += sred[j]; tG2 += sred[16+j]; tRG += sred[32+j];
            tR += sred[48+j]; tR2 += sred[64+j];
        }
        ws[WS_MOM + b*5 + 0] = tG;
        ws[WS_MOM + b*5 + 1] = tG2;
        ws[WS_MOM + b*5 + 2] = tRG;
        ws[WS_MOM + b*5 + 3] = tR;
        ws[WS_MOM + b*5 + 4] = tR2;
        ws[WS_META + b*2]     = qmin;
        ws[WS_META + b*2 + 1] = qinv;
    }
}

// n4: 149 x 256: global stats from 80 uniform floats; lerp + BN2 + ReLU.
__global__ __launch_bounds__(256) void n4_out(
    const float* __restrict__ ws, const float* __restrict__ gammap,
    const float* __restrict__ g2, const float* __restrict__ be2,
    float* __restrict__ out)
{
    const float gamma = gammap[0];
    float sy = 0.f, sy2 = 0.f;
    #pragma unroll
    for (int j = 0; j < BB; ++j) {              // fixed order, uniform loads
        const float tG  = ws[WS_MOM + j*5 + 0];
        const float tG2 = ws[WS_MOM + j*5 + 1];
        const float tRG = ws[WS_MOM + j*5 + 2];
        const float tR  = ws[WS_MOM + j*5 + 3];
        const float tR2 = ws[WS_MOM + j*5 + 4];
        sy  += tR + gamma*tG;
        sy2 += tR2 + 2.f*gamma*tRG + gamma*gamma*tG2;
    }
    const float invn = 1.f/(float)TOT;
    const float my = sy*invn;
    const float vy = sy2*invn - my*my;
    const float sc = g2[0]*rsqrtf(vy + EPSF);
    const float sh = be2[0] - my*sc;

    const int item = blockIdx.x*256 + threadIdx.x;
    if (item >= TOT) return;
    const int b = item / NN;
    const float4 v = ((const float4*)(ws + WS_KPQR))[item];
    const float qmin = ws[WS_META + b*2], qinv = ws[WS_META + b*2 + 1];
    float uu = fminf(fmaxf((v.z - qmin)*qinv, 0.f), (float)(TT-1));
    int i = (int)uu; if (i > TT-2) i = TT-2;
    const float f = uu - (float)i;
    const float g0 = ws[WS_TAB + b*TT + i];
    const float g1v = ws[WS_TAB + b*TT + i + 1];
    const float y = v.w + gamma*fmaf(f, g1v-g0, g0);
    out[item] = fmaxf(fmaf(y, sc, sh), 0.f);
}

extern "C" void kernel_launch(void* const* d_in, const int* in_sizes, int n_in,
                              void* d_out, int out_size, void* d_ws, size_t ws_size,
                              hipStream_t stream)
{
    const float* z    = (const float*)d_in[0];
    const float* w1   = (const float*)d_in[1];
    // d_in[2] = b1 (cancels in train-mode BN1)
    const float* g1   = (const float*)d_in[3];
    const float* be1  = (const float*)d_in[4];
    const float* wq   = (const float*)d_in[5];
    const float* bq   = (const float*)d_in[6];
    const float* wk   = (const float*)d_in[7];
    const float* bk   = (const float*)d_in[8];
    const float* wv   = (const float*)d_in[9];
    const float* bv   = (const float*)d_in[10];
    const float* gamma= (const float*)d_in[11];
    const float* w2   = (const float*)d_in[12];
    const float* b2   = (const float*)d_in[13];
    const float* g2   = (const float*)d_in[14];
    const float* be2  = (const float*)d_in[15];
    float* ws  = (float*)d_ws;
    float* out = (float*)d_out;

    n0_zstats<<<NZB, 256, 0, stream>>>(z, ws);

    n1_kpqr<<<dim3(NXB, BB), 256, 0, stream>>>(
        z, w1, g1, be1, wq, bq, wk, bk, wv, bv, w2, b2, ws);

    n2_table<<<dim3(TT, BB), 256, 0, stream>>>(ws, ws);

    n3_moments<<<BB, 1024, 0, stream>>>(ws, ws);

    n4_out<<<NB_OUT, 256, 0, stream>>>(ws, gamma, g2, be2, out);
}